// Round 2
// baseline (565.184 us; speedup 1.0000x reference)
//
#include <hip/hip_runtime.h>
#include <hip/hip_bf16.h>
#include <math.h>

#define B 4
#define C 256
#define T 8
#define H 128
#define WW 64
#define IC 128
#define S 64          // t*STRIPE tokens
#define REGION 1024   // HS*WW contiguous floats per stripe region
#define NREGION 65536 // B*C*T*8
#define EPS 1e-5f

// ---------------- K0: weight transposes ----------------
// gwT/twT/pwT[ch*IC + i] = w[i*C + ch]   (proj weights, read coalesced over i)
// WwT[i*C + ch]          = W_w[ch*IC+i]  (out-proj weight, read coalesced over ch)
__global__ void transpose_kernel(const float* __restrict__ gw,
                                 const float* __restrict__ tw,
                                 const float* __restrict__ pw,
                                 const float* __restrict__ Ww,
                                 float* __restrict__ gwT, float* __restrict__ twT,
                                 float* __restrict__ pwT, float* __restrict__ WwT) {
    int t = blockIdx.x * blockDim.x + threadIdx.x;   // 0..131071
    int m = t >> 15;          // matrix id 0..3
    int e = t & 32767;
    if (m < 3) {
        int ch = e >> 7, i = e & 127;                // out idx e = ch*128+i
        const float* src = (m == 0) ? gw : (m == 1) ? tw : pw;
        float* dst = (m == 0) ? gwT : (m == 1) ? twT : pwT;
        dst[e] = src[i * C + ch];
    } else {
        int i = e >> 8, ch = e & 255;                // out idx e = i*256+ch
        WwT[e] = Ww[ch * IC + i];
    }
}

// ---------------- K1: stripe mean pool (wave-per-region, no LDS) ----------
// 1024 blocks x 256 thr = 4096 waves; each wave reduces 16 contiguous
// 4 KiB regions. Output written TRANSPOSED: dnT[(b*S+s)*C + ch].
__global__ void pool_kernel(const float* __restrict__ x, float* __restrict__ dnT) {
    int tid = threadIdx.x;
    int lane = tid & 63;
    int wgid = (blockIdx.x << 2) | (tid >> 6);       // global wave id 0..4095
    int r0 = wgid << 4;                              // first region
    for (int k = 0; k < 16; ++k) {
        int r = r0 + k;
        const float4* xr = (const float4*)(x + (size_t)r * REGION);
        float4 a = xr[lane];
        float4 b = xr[lane + 64];
        float4 c = xr[lane + 128];
        float4 d = xr[lane + 192];
        float sum = (a.x + a.y + a.z + a.w) + (b.x + b.y + b.z + b.w)
                  + (c.x + c.y + c.z + c.w) + (d.x + d.y + d.z + d.w);
        #pragma unroll
        for (int off = 32; off > 0; off >>= 1)
            sum += __shfl_xor(sum, off, 64);
        if (lane == 0) {
            // r bits: [15:14]=b, [13:6]=ch, [5:0]=s  ->  dnT idx b<<14 | s<<8 | ch
            int idx = (r & 0xC000) | ((r & 63) << 8) | ((r >> 6) & 255);
            dnT[idx] = sum * (1.0f / (float)REGION);
        }
    }
}

// ---------------- K2: g/theta/phi projections (coalesced weights) -------
// 256 blocks (b,s) x 128 threads; thread i computes g/th/ph[b,s,i].
__global__ void proj_kernel(const float* __restrict__ dnT,
                            const float* __restrict__ gwT, const float* __restrict__ gb,
                            const float* __restrict__ twT, const float* __restrict__ tb,
                            const float* __restrict__ pwT, const float* __restrict__ pb,
                            float* __restrict__ g, float* __restrict__ th,
                            float* __restrict__ ph) {
    int blk = blockIdx.x;             // = b*64+s
    __shared__ float dloc[C];
    const float2* dr = (const float2*)(dnT + (size_t)blk * C);
    ((float2*)dloc)[threadIdx.x] = dr[threadIdx.x];
    __syncthreads();
    int i = threadIdx.x;              // 0..127
    float ag = gb[i], at = tb[i], ap = pb[i];
    #pragma unroll 4
    for (int ch = 0; ch < C; ++ch) {
        float d = dloc[ch];
        int o = (ch << 7) + i;
        ag = fmaf(d, gwT[o], ag);
        at = fmaf(d, twT[o], at);
        ap = fmaf(d, pwT[o], ap);
    }
    size_t o = ((size_t)blk) * IC + i;
    g[o] = ag; th[o] = at; ph[o] = ap;
}

// ---------------- K3: attention + output proj + BN (fused) --------------
// 256 blocks (b,s) x 256 threads.
__global__ void attn_out_kernel(const float* __restrict__ g,
                                const float* __restrict__ th,
                                const float* __restrict__ ph,
                                const float* __restrict__ WwT,
                                const float* __restrict__ Wb,
                                const float* __restrict__ gamma,
                                const float* __restrict__ beta,
                                const float* __restrict__ mean,
                                const float* __restrict__ var,
                                float* __restrict__ wy) {
    int blk = blockIdx.x;
    int b = blk >> 6, s = blk & 63;
    int tid = threadIdx.x;
    int wave = tid >> 6, lane = tid & 63;
    __shared__ float thloc[IC];
    __shared__ float p[S];
    __shared__ float yl[IC];
    if (tid < IC) thloc[tid] = th[((size_t)blk) * IC + tid];
    __syncthreads();
    // scores: wave w handles tokens r = w*16 .. w*16+15, coalesced ph reads
    for (int k = 0; k < 16; ++k) {
        int r = (wave << 4) + k;
        const float* phr = ph + ((size_t)(b * S + r)) * IC;
        float v = thloc[lane] * phr[lane];
        v = fmaf(thloc[lane + 64], phr[lane + 64], v);
        #pragma unroll
        for (int off = 32; off > 0; off >>= 1)
            v += __shfl_xor(v, off, 64);
        if (lane == 0) p[r] = v;
    }
    __syncthreads();
    // softmax over the 64 scores (wave 0)
    if (tid < 64) {
        float f = p[tid];
        float m = f;
        #pragma unroll
        for (int off = 32; off > 0; off >>= 1)
            m = fmaxf(m, __shfl_xor(m, off, 64));
        float e = __expf(f - m);
        float sum = e;
        #pragma unroll
        for (int off = 32; off > 0; off >>= 1)
            sum += __shfl_xor(sum, off, 64);
        p[tid] = e / sum;
    }
    __syncthreads();
    // y row (threads 0..127, coalesced g reads)
    if (tid < IC) {
        float acc = 0.0f;
        #pragma unroll 4
        for (int r = 0; r < S; ++r)
            acc = fmaf(p[r], g[((size_t)(b * S + r)) * IC + tid], acc);
        yl[tid] = acc;
    }
    __syncthreads();
    // output projection: thread ch, coalesced WwT reads; + BatchNorm(eval)
    int ch = tid;
    float acc = Wb[ch];
    #pragma unroll 4
    for (int i = 0; i < IC; ++i)
        acc = fmaf(yl[i], WwT[(i << 8) + ch], acc);
    float inv = gamma[ch] * rsqrtf(var[ch] + EPS);
    wy[((size_t)(b * C + ch)) * S + s] = (acc - mean[ch]) * inv + beta[ch];
}

// ---------------- K5: broadcast residual add -----------------------------
__global__ void add_kernel(const float* __restrict__ x,
                           const float* __restrict__ wy,
                           float* __restrict__ out) {
    size_t f = (size_t)blockIdx.x * blockDim.x + threadIdx.x;
    const float4* x4 = (const float4*)x;
    float4* o4 = (float4*)out;
    float4 v = x4[f];
    float a = wy[f >> 8];
    v.x += a; v.y += a; v.z += a; v.w += a;
    o4[f] = v;
}

extern "C" void kernel_launch(void* const* d_in, const int* in_sizes, int n_in,
                              void* d_out, int out_size, void* d_ws, size_t ws_size,
                              hipStream_t stream) {
    const float* x       = (const float*)d_in[0];
    const float* g_w     = (const float*)d_in[1];
    const float* g_b     = (const float*)d_in[2];
    const float* theta_w = (const float*)d_in[3];
    const float* theta_b = (const float*)d_in[4];
    const float* phi_w   = (const float*)d_in[5];
    const float* phi_b   = (const float*)d_in[6];
    const float* W_w     = (const float*)d_in[7];
    const float* W_b     = (const float*)d_in[8];
    const float* bn_g    = (const float*)d_in[9];
    const float* bn_b    = (const float*)d_in[10];
    const float* bn_m    = (const float*)d_in[11];
    const float* bn_v    = (const float*)d_in[12];
    float* out = (float*)d_out;

    // workspace layout (floats)
    float* ws  = (float*)d_ws;
    float* dnT = ws;                   // B*S*C  = 65536  (b,s,ch)
    float* gwT = dnT + B * S * C;      // 32768
    float* twT = gwT + C * IC;         // 32768
    float* pwT = twT + C * IC;         // 32768
    float* WwT = pwT + C * IC;         // 32768
    float* g   = WwT + C * IC;         // B*S*IC = 32768
    float* th  = g   + B * S * IC;     // 32768
    float* ph  = th  + B * S * IC;     // 32768
    float* wy  = ph  + B * S * IC;     // B*C*S  = 65536

    transpose_kernel<<<512, 256, 0, stream>>>(g_w, theta_w, phi_w, W_w,
                                              gwT, twT, pwT, WwT);

    pool_kernel<<<1024, 256, 0, stream>>>(x, dnT);

    proj_kernel<<<B * S, IC, 0, stream>>>(dnT, gwT, g_b, twT, theta_b,
                                          pwT, phi_b, g, th, ph);

    attn_out_kernel<<<B * S, 256, 0, stream>>>(g, th, ph, WwT, W_b,
                                               bn_g, bn_b, bn_m, bn_v, wy);

    const size_t nVec4 = (size_t)B * C * T * H * WW / 4;  // 16.7M
    add_kernel<<<(int)(nVec4 / 256), 256, 0, stream>>>(x, wy, out);
}